// Round 1
// baseline (3140.369 us; speedup 1.0000x reference)
//
#include <hip/hip_runtime.h>
#include <cmath>

constexpr int kC  = 96;
constexpr int kH  = 256;
constexpr int kW  = 256;
constexpr int kHW = kH * kW;   // 65536

// ---------------- bias table: bias_tab[h][i][j], h<6, i,j<64 ----------------
__global__ void bias_kernel(const float* __restrict__ w1, const float* __restrict__ b1,
                            const float* __restrict__ w2, const float* __restrict__ b2,
                            float* __restrict__ bias_tab) {
  int i = blockIdx.x;   // query token 0..63
  int j = threadIdx.x;  // key token 0..63
  float dy = (float)((i >> 3) - (j >> 3));
  float dx = (float)((i & 7) - (j & 7));
  float r0 = copysignf(log1pf(fabsf(dy)), dy);
  float r1 = copysignf(log1pf(fabsf(dx)), dx);
  float acc[6];
#pragma unroll
  for (int h = 0; h < 6; ++h) acc[h] = b2[h];
  for (int t = 0; t < 256; ++t) {
    float hv = fmaf(r0, w1[t], fmaf(r1, w1[256 + t], b1[t]));
    hv = fmaxf(hv, 0.f);
#pragma unroll
    for (int h = 0; h < 6; ++h) acc[h] = fmaf(hv, w2[t * 6 + h], acc[h]);
  }
#pragma unroll
  for (int h = 0; h < 6; ++h) bias_tab[h * 4096 + i * 64 + j] = acc[h];
}

// ---------------- fused QKV pointwise conv -> qkv NCHW [B][288][H][W] -------
__global__ __launch_bounds__(256) void qkv_kernel(
    const float* __restrict__ X,
    const float* __restrict__ qk_w, const float* __restrict__ qk_b,
    const float* __restrict__ v_w,  const float* __restrict__ v_b,
    float* __restrict__ qkv) {
  __shared__ float xs[128][97];
  int t = threadIdx.x;
  int xbase = blockIdx.x * 128;      // 0 or 128
  int y = blockIdx.y;                // row
  int b = blockIdx.z;
  const float* xin = X + ((size_t)b * kC) * kHW + (size_t)y * kW + xbase;
#pragma unroll
  for (int i = 0; i < 48; ++i) {
    int idx = i * 256 + t;
    int ic = idx >> 7, px = idx & 127;
    xs[px][ic] = xin[(size_t)ic * kHW + px];
  }
  __syncthreads();
  int px  = t & 127;
  int och = t >> 7;                  // wave-uniform: waves 0,1 -> 0; waves 2,3 -> 1
  float* outp = qkv + ((size_t)b * 288) * kHW + (size_t)y * kW + xbase + px;
  for (int ocg = 0; ocg < 9; ++ocg) {
    int oc0 = ocg * 32 + och * 16;   // 16 consecutive out channels per thread
    const float* wbase;
    const float* bbase;
    int orel;
    if (oc0 < 192) { wbase = qk_w; bbase = qk_b; orel = oc0; }
    else           { wbase = v_w;  bbase = v_b;  orel = oc0 - 192; }
    float acc[16];
#pragma unroll
    for (int k = 0; k < 16; ++k) acc[k] = bbase[orel + k];
#pragma unroll 4
    for (int ic = 0; ic < 96; ++ic) {
      float xv = xs[px][ic];
#pragma unroll
      for (int k = 0; k < 16; ++k)
        acc[k] = fmaf(xv, wbase[(size_t)(orel + k) * 96 + ic], acc[k]);
    }
#pragma unroll
    for (int k = 0; k < 16; ++k)
      outp[(size_t)(oc0 + k) * kHW] = acc[k];
  }
}

// ---------------- window attention: writes attn_out into d_out --------------
// block = 4 windows x 1 head, 256 threads; lane = query row within window
__global__ __launch_bounds__(256) void attn_kernel(
    const float* __restrict__ qkv, const float* __restrict__ bias_tab,
    float* __restrict__ out) {
  __shared__ float bs[64 * 65];        // bias[i][j] padded, per head
  __shared__ float ks[4][64 * 16];
  __shared__ float vs[4][64 * 16];
  int t = threadIdx.x;
  int wv = t >> 6, lane = t & 63;
  int h = blockIdx.y;
  int wid = blockIdx.x * 4 + wv;       // 0..4095
  int b  = wid >> 10;
  int wy = (wid >> 5) & 31, wx = wid & 31;
  int gy = wy * 8 + (lane >> 3), gx = wx * 8 + (lane & 7);
  size_t pixoff = (size_t)gy * kW + gx;
  const float* qp = qkv + ((size_t)b * 288 + h * 16) * kHW + pixoff;
  const float* kp = qp + (size_t)96 * kHW;
  const float* vp = qp + (size_t)192 * kHW;

  float q[16], kv[16], vv[16];
#pragma unroll
  for (int d = 0; d < 16; ++d) {
    q[d]  = qp[(size_t)d * kHW] * 0.25f;   // scale = hd^-0.5
    kv[d] = kp[(size_t)d * kHW];
    vv[d] = vp[(size_t)d * kHW];
  }
  float4* kr4 = (float4*)&ks[wv][lane * 16];
  float4* vr4 = (float4*)&vs[wv][lane * 16];
#pragma unroll
  for (int d4 = 0; d4 < 4; ++d4) {
    kr4[d4] = make_float4(kv[d4 * 4], kv[d4 * 4 + 1], kv[d4 * 4 + 2], kv[d4 * 4 + 3]);
    vr4[d4] = make_float4(vv[d4 * 4], vv[d4 * 4 + 1], vv[d4 * 4 + 2], vv[d4 * 4 + 3]);
  }
  // bias rows: coalesced global read, conflict-free LDS write
  {
    const float* bp = bias_tab + h * 4096;
#pragma unroll
    for (int r0 = 0; r0 < 16; ++r0) {
      int r = wv * 16 + r0;
      bs[r * 65 + lane] = bp[r * 64 + lane];
    }
  }
  __syncthreads();

  const float* krow = ks[wv];
  const float* vrow = vs[wv];
  float s[64];
#pragma unroll 8
  for (int j = 0; j < 64; ++j) {
    float dot = bs[lane * 65 + j];
#pragma unroll
    for (int d = 0; d < 16; ++d) dot = fmaf(q[d], krow[j * 16 + d], dot);
    s[j] = dot;
  }
  float m = s[0];
#pragma unroll
  for (int j = 1; j < 64; ++j) m = fmaxf(m, s[j]);
  float sum = 0.f;
#pragma unroll
  for (int j = 0; j < 64; ++j) { s[j] = expf(s[j] - m); sum += s[j]; }
  float r = 1.f / sum;
  float o[16];
#pragma unroll
  for (int d = 0; d < 16; ++d) o[d] = 0.f;
#pragma unroll 8
  for (int j = 0; j < 64; ++j) {
    float p = s[j];
#pragma unroll
    for (int d = 0; d < 16; ++d) o[d] = fmaf(p, vrow[j * 16 + d], o[d]);
  }
  float* op = out + ((size_t)b * kC + h * 16) * kHW + pixoff;
#pragma unroll
  for (int d = 0; d < 16; ++d) op[(size_t)d * kHW] = o[d] * r;
}

// ---------------- 3x3 conv with reflect padding -----------------------------
// block 256 = 16x16 pixels, 32 out-channels per block (gridDim.z = B*3)
template <bool RELU, bool ADD>
__global__ __launch_bounds__(256) void conv_kernel(
    const float* __restrict__ in, size_t in_bstride,
    const float* __restrict__ w, const float* __restrict__ bias,
    float* __restrict__ out, size_t out_bstride) {
  __shared__ float tile[18 * 18];
  int t = threadIdx.x;
  int tx = t & 15, ty = t >> 4;
  int x0 = blockIdx.x * 16, y0 = blockIdx.y * 16;
  int b = blockIdx.z / 3, ocg = blockIdx.z % 3;
  int oc0 = ocg * 32;
  const float* inb = in + (size_t)b * in_bstride;
  float acc[32];
#pragma unroll
  for (int oc = 0; oc < 32; ++oc) acc[oc] = 0.f;

  for (int ic = 0; ic < 96; ++ic) {
    for (int idx = t; idx < 324; idx += 256) {
      int ly = idx / 18, lx = idx % 18;
      int gy = y0 - 1 + ly; gy = gy < 0 ? -gy : (gy > 255 ? 510 - gy : gy);
      int gx = x0 - 1 + lx; gx = gx < 0 ? -gx : (gx > 255 ? 510 - gx : gx);
      tile[idx] = inb[(size_t)ic * kHW + (size_t)gy * kW + gx];
    }
    __syncthreads();
    float xv[9];
#pragma unroll
    for (int dy = 0; dy < 3; ++dy)
#pragma unroll
      for (int dx = 0; dx < 3; ++dx)
        xv[dy * 3 + dx] = tile[(ty + dy) * 18 + tx + dx];
    const float* wic = w + ((size_t)oc0 * 96 + ic) * 9;
#pragma unroll
    for (int oc = 0; oc < 32; ++oc) {
      const float* wp = wic + (size_t)oc * 96 * 9;
#pragma unroll
      for (int k = 0; k < 9; ++k) acc[oc] = fmaf(xv[k], wp[k], acc[oc]);
    }
    __syncthreads();
  }
  float* outb = out + (size_t)b * out_bstride;
  int gy = y0 + ty, gx = x0 + tx;
#pragma unroll
  for (int oc = 0; oc < 32; ++oc) {
    float v = acc[oc] + bias[oc0 + oc];
    if (RELU) v = fmaxf(v, 0.f);
    float* po = outb + (size_t)(oc0 + oc) * kHW + (size_t)gy * kW + gx;
    if (ADD) v += *po;
    *po = v;
  }
}

// ---------------- final 1x1 projection, in-place on d_out -------------------
__global__ __launch_bounds__(256) void proj_kernel(
    const float* __restrict__ w, const float* __restrict__ bias,
    float* __restrict__ out) {
  __shared__ float xs[128][97];
  int t = threadIdx.x;
  int xb = (blockIdx.x & 1) * 128;
  int y = blockIdx.x >> 1;
  int b = blockIdx.y;
  float* base = out + (size_t)b * kC * kHW + (size_t)y * kW + xb;
#pragma unroll
  for (int i = 0; i < 48; ++i) {
    int idx = i * 256 + t;
    int ic = idx >> 7, px = idx & 127;
    xs[px][ic] = base[(size_t)ic * kHW + px];
  }
  __syncthreads();
  int px = t & 127, och = t >> 7;    // och wave-uniform
  float acc[48];
#pragma unroll
  for (int k = 0; k < 48; ++k) acc[k] = bias[och * 48 + k];
#pragma unroll 4
  for (int ic = 0; ic < 96; ++ic) {
    float xv = xs[px][ic];
#pragma unroll
    for (int k = 0; k < 48; ++k)
      acc[k] = fmaf(xv, w[(size_t)(och * 48 + k) * 96 + ic], acc[k]);
  }
#pragma unroll
  for (int k = 0; k < 48; ++k)
    base[(size_t)(och * 48 + k) * kHW + px] = acc[k];
}

extern "C" void kernel_launch(void* const* d_in, const int* in_sizes, int n_in,
                              void* d_out, int out_size, void* d_ws, size_t ws_size,
                              hipStream_t stream) {
  const float* X       = (const float*)d_in[0];
  const float* V_w     = (const float*)d_in[1];
  const float* V_b     = (const float*)d_in[2];
  const float* QK_w    = (const float*)d_in[3];
  const float* QK_b    = (const float*)d_in[4];
  const float* meta_w1 = (const float*)d_in[5];
  const float* meta_b1 = (const float*)d_in[6];
  const float* meta_w2 = (const float*)d_in[7];
  const float* meta_b2 = (const float*)d_in[8];
  const float* conv1_w = (const float*)d_in[9];
  const float* conv1_b = (const float*)d_in[10];
  const float* conv2_w = (const float*)d_in[11];
  const float* conv2_b = (const float*)d_in[12];
  const float* proj_w  = (const float*)d_in[13];
  const float* proj_b  = (const float*)d_in[14];
  float* out = (float*)d_out;

  float* ws = (float*)d_ws;
  float* bias_tab = ws;                  // 24576 floats
  float* qkv = ws + 262144;              // [B][288][H][W] = 75,497,472 floats
  float* t1  = qkv;                      // conv1 out aliases Q channels (0..95)
                                         // per batch; attention has consumed
                                         // them before conv1 runs (same stream)

  bias_kernel<<<dim3(64), dim3(64), 0, stream>>>(meta_w1, meta_b1, meta_w2, meta_b2, bias_tab);

  qkv_kernel<<<dim3(2, 256, 4), dim3(256), 0, stream>>>(X, QK_w, QK_b, V_w, V_b, qkv);

  attn_kernel<<<dim3(1024, 6), dim3(256), 0, stream>>>(qkv, bias_tab, out);

  // conv1: reads V channels (192..287) of qkv, writes channels 0..95 region
  conv_kernel<true, false><<<dim3(16, 16, 12), dim3(256), 0, stream>>>(
      qkv + (size_t)192 * kHW, (size_t)288 * kHW, conv1_w, conv1_b,
      t1, (size_t)288 * kHW);

  // conv2: reads t1, adds attention output already in d_out, writes d_out
  conv_kernel<false, true><<<dim3(16, 16, 12), dim3(256), 0, stream>>>(
      t1, (size_t)288 * kHW, conv2_w, conv2_b,
      out, (size_t)96 * kHW);

  proj_kernel<<<dim3(512, 4), dim3(256), 0, stream>>>(proj_w, proj_b, out);
}

// Round 2
// 1396.779 us; speedup vs baseline: 2.2483x; 2.2483x over previous
//
#include <hip/hip_runtime.h>
#include <cmath>

typedef short  short8 __attribute__((ext_vector_type(8)));
typedef float  f32x4  __attribute__((ext_vector_type(4)));
typedef unsigned short us8 __attribute__((ext_vector_type(8)));
typedef unsigned short us4 __attribute__((ext_vector_type(4)));

constexpr int kHW = 65536;           // 256*256
constexpr int kP  = 262144;          // 4 * kHW total pixels

__device__ __forceinline__ unsigned short f2bf(float x) {
  unsigned u = __builtin_bit_cast(unsigned, x);
  u += 0x7fffu + ((u >> 16) & 1u);
  return (unsigned short)(u >> 16);
}
__device__ __forceinline__ float bf2f(unsigned short h) {
  unsigned u = ((unsigned)h) << 16;
  return __builtin_bit_cast(float, u);
}
__device__ __forceinline__ void split2(float v, unsigned short& h, unsigned short& l) {
  unsigned short hh = f2bf(v);
  h = hh;
  l = f2bf(v - bf2f(hh));
}

// ---------------- bias table: bias_tab[h][i][j], h<6, i,j<64 ----------------
__global__ void bias_kernel(const float* __restrict__ w1, const float* __restrict__ b1,
                            const float* __restrict__ w2, const float* __restrict__ b2,
                            float* __restrict__ bias_tab) {
  int i = blockIdx.x;
  int j = threadIdx.x;
  float dy = (float)((i >> 3) - (j >> 3));
  float dx = (float)((i & 7) - (j & 7));
  float r0 = copysignf(log1pf(fabsf(dy)), dy);
  float r1 = copysignf(log1pf(fabsf(dx)), dx);
  float acc[6];
#pragma unroll
  for (int h = 0; h < 6; ++h) acc[h] = b2[h];
  for (int t = 0; t < 256; ++t) {
    float hv = fmaf(r0, w1[t], fmaf(r1, w1[256 + t], b1[t]));
    hv = fmaxf(hv, 0.f);
#pragma unroll
    for (int h = 0; h < 6; ++h) acc[h] = fmaf(hv, w2[t * 6 + h], acc[h]);
  }
#pragma unroll
  for (int h = 0; h < 6; ++h) bias_tab[h * 4096 + i * 64 + j] = acc[h];
}

// ---------------- weight prep: fp32 -> bf16 hi/lo planes ---------------------
// Wq: [288][96]  (rows 0..191 = QK_w, rows 192..287 = V_w)
// W1/W2: [delta][oc][ic], delta = dy*3+dx   Wp: [96][96]
__global__ void prep_weights(const float* __restrict__ qk_w, const float* __restrict__ v_w,
                             const float* __restrict__ c1w, const float* __restrict__ c2w,
                             const float* __restrict__ pjw,
                             unsigned short* __restrict__ Wqh, unsigned short* __restrict__ Wql,
                             unsigned short* __restrict__ W1h, unsigned short* __restrict__ W1l,
                             unsigned short* __restrict__ W2h, unsigned short* __restrict__ W2l,
                             unsigned short* __restrict__ Wph, unsigned short* __restrict__ Wpl) {
  int i = blockIdx.x * 256 + threadIdx.x;
  if (i < 27648) {
    float v = (i < 18432) ? qk_w[i] : v_w[i - 18432];
    split2(v, Wqh[i], Wql[i]);
  }
  if (i < 82944) {
    int dlt = i / 9216;
    int oc  = (i / 96) % 96;
    int ic  = i % 96;
    int src = (oc * 96 + ic) * 9 + dlt;
    split2(c1w[src], W1h[i], W1l[i]);
    split2(c2w[src], W2h[i], W2l[i]);
  }
  if (i < 9216) split2(pjw[i], Wph[i], Wpl[i]);
}

// ---------------- X: NCHW fp32 -> NHWC bf16 hi/lo ---------------------------
__global__ __launch_bounds__(256) void split_x(const float* __restrict__ X,
                                               unsigned short* __restrict__ Xh,
                                               unsigned short* __restrict__ Xl) {
  __shared__ float tile[96][65];
  int t = threadIdx.x;
  size_t p0 = (size_t)blockIdx.x * 64;
  int b = (int)(p0 >> 16), pix = (int)(p0 & 65535);
  const float* xb = X + (size_t)b * 96 * kHW + pix;
#pragma unroll
  for (int i = 0; i < 24; ++i) {
    int ic = (t >> 6) + i * 4;
    tile[ic][t & 63] = xb[(size_t)ic * kHW + (t & 63)];
  }
  __syncthreads();
  int px = t >> 2;
  size_t outbase = (p0 + px) * 96;
#pragma unroll
  for (int cc = 0; cc < 3; ++cc) {
    int c = (t & 3) + cc * 4;      // chunk of 8 channels
    us8 h8, l8;
#pragma unroll
    for (int j = 0; j < 8; ++j) {
      unsigned short hh, ll;
      split2(tile[c * 8 + j][px], hh, ll);
      h8[j] = hh; l8[j] = ll;
    }
    *(us8*)(Xh + outbase + c * 8) = h8;
    *(us8*)(Xl + outbase + c * 8) = l8;
  }
}

// ---------------- shared MFMA core: D[96 oc][256 px] = W * X^T ---------------
// A-frag: 16 oc rows, k fastest (W [oc][ic] hi/lo).  B-frag: 16 px cols,
// k fastest (X NHWC [p][ic] hi/lo).  3-term split: hh + hl + lh.
__device__ __forceinline__ void gemm_core(
    const unsigned short* __restrict__ Wh, const unsigned short* __restrict__ Wl,
    const unsigned short* __restrict__ Xh, const unsigned short* __restrict__ Xl,
    size_t px0, int lane, f32x4 (&acc)[6][4]) {
  int col = lane & 15, g = lane >> 4;
  const char* aH = (const char*)Wh + (size_t)(col * 96 + g * 8) * 2;
  const char* aL = (const char*)Wl + (size_t)(col * 96 + g * 8) * 2;
  const char* bH = (const char*)Xh + ((px0 + col) * 96 + g * 8) * 2;
  const char* bL = (const char*)Xl + ((px0 + col) * 96 + g * 8) * 2;
#pragma unroll
  for (int ks = 0; ks < 3; ++ks) {
    short8 Ahf[6], Alf[6], Bhf[4], Blf[4];
#pragma unroll
    for (int mf = 0; mf < 6; ++mf) {
      Ahf[mf] = *(const short8*)(aH + (size_t)(mf * 16 * 96 + ks * 32) * 2);
      Alf[mf] = *(const short8*)(aL + (size_t)(mf * 16 * 96 + ks * 32) * 2);
    }
#pragma unroll
    for (int nf = 0; nf < 4; ++nf) {
      Bhf[nf] = *(const short8*)(bH + (size_t)(nf * 16 * 96 + ks * 32) * 2);
      Blf[nf] = *(const short8*)(bL + (size_t)(nf * 16 * 96 + ks * 32) * 2);
    }
#pragma unroll
    for (int mf = 0; mf < 6; ++mf)
#pragma unroll
      for (int nf = 0; nf < 4; ++nf) {
        acc[mf][nf] = __builtin_amdgcn_mfma_f32_16x16x32_bf16(Ahf[mf], Bhf[nf], acc[mf][nf], 0, 0, 0);
        acc[mf][nf] = __builtin_amdgcn_mfma_f32_16x16x32_bf16(Ahf[mf], Blf[nf], acc[mf][nf], 0, 0, 0);
        acc[mf][nf] = __builtin_amdgcn_mfma_f32_16x16x32_bf16(Alf[mf], Bhf[nf], acc[mf][nf], 0, 0, 0);
      }
  }
}

// ---------------- QKV GEMM: z=0 Q(bf16), z=1 K(bf16), z=2 V(hi/lo) ----------
__global__ __launch_bounds__(256, 2) void qkv_gemm(
    const unsigned short* __restrict__ Wqh, const unsigned short* __restrict__ Wql,
    const unsigned short* __restrict__ Xh, const unsigned short* __restrict__ Xl,
    const float* __restrict__ qk_b, const float* __restrict__ v_b,
    unsigned short* __restrict__ Qb, unsigned short* __restrict__ Kb,
    unsigned short* __restrict__ Vh, unsigned short* __restrict__ Vl) {
  int t = threadIdx.x, wv = t >> 6, lane = t & 63;
  int z = blockIdx.y;
  size_t px0 = (size_t)blockIdx.x * 256 + wv * 64;
  f32x4 acc[6][4];
#pragma unroll
  for (int m = 0; m < 6; ++m)
#pragma unroll
    for (int n = 0; n < 4; ++n) acc[m][n] = (f32x4)0.f;
  gemm_core(Wqh + z * 9216, Wql + z * 9216, Xh, Xl, px0, lane, acc);
  int col = lane & 15, g = lane >> 4;
  const float* bias = (z == 0) ? qk_b : (z == 1 ? qk_b + 96 : v_b);
#pragma unroll
  for (int mf = 0; mf < 6; ++mf) {
    int oc0 = mf * 16 + g * 4;
    f32x4 bv;
#pragma unroll
    for (int r = 0; r < 4; ++r) bv[r] = bias[oc0 + r];
#pragma unroll
    for (int nf = 0; nf < 4; ++nf) {
      size_t p = px0 + nf * 16 + col;
      f32x4 v = acc[mf][nf] + bv;
      size_t off = p * 96 + oc0;
      if (z == 2) {
        us4 oh, ol;
#pragma unroll
        for (int r = 0; r < 4; ++r) { unsigned short hh, ll; split2(v[r], hh, ll); oh[r] = hh; ol[r] = ll; }
        *(us4*)(Vh + off) = oh;
        *(us4*)(Vl + off) = ol;
      } else {
        us4 o;
#pragma unroll
        for (int r = 0; r < 4; ++r) o[r] = f2bf(v[r]);
        *(us4*)((z == 0 ? Qb : Kb) + off) = o;
      }
    }
  }
}

// ---------------- attention: NHWC bf16 in, NHWC fp32 out (d_out scratch) ----
__global__ __launch_bounds__(256) void attn_kernel(
    const unsigned short* __restrict__ Qb, const unsigned short* __restrict__ Kb,
    const unsigned short* __restrict__ Vh, const unsigned short* __restrict__ Vl,
    const float* __restrict__ bias_tab, float* __restrict__ out) {
  __shared__ float bs[64 * 65];
  __shared__ float ks_[4][64 * 16];
  __shared__ float vs_[4][64 * 16];
  int t = threadIdx.x;
  int wv = t >> 6, lane = t & 63;
  int h = blockIdx.y;
  int wid = blockIdx.x * 4 + wv;
  int b = wid >> 10, wy = (wid >> 5) & 31, wx = wid & 31;
  size_t p = ((size_t)b << 16) + (size_t)(wy * 8 + (lane >> 3)) * 256 + wx * 8 + (lane & 7);
  size_t base = p * 96 + h * 16;
  us8 q0 = *(const us8*)(Qb + base), q1 = *(const us8*)(Qb + base + 8);
  us8 k0 = *(const us8*)(Kb + base), k1 = *(const us8*)(Kb + base + 8);
  us8 vh0 = *(const us8*)(Vh + base), vh1 = *(const us8*)(Vh + base + 8);
  us8 vl0 = *(const us8*)(Vl + base), vl1 = *(const us8*)(Vl + base + 8);
  float q[16];
#pragma unroll
  for (int d = 0; d < 8; ++d) {
    q[d]     = bf2f(q0[d]) * 0.25f;
    q[8 + d] = bf2f(q1[d]) * 0.25f;
  }
  float4* kr4 = (float4*)&ks_[wv][lane * 16];
  float4* vr4 = (float4*)&vs_[wv][lane * 16];
#pragma unroll
  for (int d4 = 0; d4 < 2; ++d4) {
    kr4[d4]     = make_float4(bf2f(k0[d4*4]), bf2f(k0[d4*4+1]), bf2f(k0[d4*4+2]), bf2f(k0[d4*4+3]));
    kr4[2 + d4] = make_float4(bf2f(k1[d4*4]), bf2f(k1[d4*4+1]), bf2f(k1[d4*4+2]), bf2f(k1[d4*4+3]));
    vr4[d4]     = make_float4(bf2f(vh0[d4*4]) + bf2f(vl0[d4*4]),
                              bf2f(vh0[d4*4+1]) + bf2f(vl0[d4*4+1]),
                              bf2f(vh0[d4*4+2]) + bf2f(vl0[d4*4+2]),
                              bf2f(vh0[d4*4+3]) + bf2f(vl0[d4*4+3]));
    vr4[2 + d4] = make_float4(bf2f(vh1[d4*4]) + bf2f(vl1[d4*4]),
                              bf2f(vh1[d4*4+1]) + bf2f(vl1[d4*4+1]),
                              bf2f(vh1[d4*4+2]) + bf2f(vl1[d4*4+2]),
                              bf2f(vh1[d4*4+3]) + bf2f(vl1[d4*4+3]));
  }
  {
    const float* bp = bias_tab + h * 4096;
#pragma unroll
    for (int r0 = 0; r0 < 16; ++r0) {
      int r = wv * 16 + r0;
      bs[r * 65 + lane] = bp[r * 64 + lane];
    }
  }
  __syncthreads();

  const float* krow = ks_[wv];
  const float* vrow = vs_[wv];
  float s[64];
#pragma unroll 8
  for (int j = 0; j < 64; ++j) {
    float dot = bs[lane * 65 + j];
#pragma unroll
    for (int d = 0; d < 16; ++d) dot = fmaf(q[d], krow[j * 16 + d], dot);
    s[j] = dot;
  }
  float m = s[0];
#pragma unroll
  for (int j = 1; j < 64; ++j) m = fmaxf(m, s[j]);
  float sum = 0.f;
#pragma unroll
  for (int j = 0; j < 64; ++j) { s[j] = expf(s[j] - m); sum += s[j]; }
  float r = 1.f / sum;
  float o[16];
#pragma unroll
  for (int d = 0; d < 16; ++d) o[d] = 0.f;
#pragma unroll 8
  for (int j = 0; j < 64; ++j) {
    float pj = s[j];
#pragma unroll
    for (int d = 0; d < 16; ++d) o[d] = fmaf(pj, vrow[j * 16 + d], o[d]);
  }
  float* op = out + base;
#pragma unroll
  for (int d = 0; d < 16; ++d) op[d] = o[d] * r;
}

// ---------------- 3x3 reflect conv as 9 shifted MFMA GEMMs -------------------
// block = one image row (256 px) x 96 oc; MODE 0: +bias, relu, split out
//                                         MODE 1: +bias, +attn(NHWC f32), split out
template <int MODE>
__global__ __launch_bounds__(256, 2) void conv_gemm(
    const unsigned short* __restrict__ Wh, const unsigned short* __restrict__ Wl,
    const unsigned short* __restrict__ Xh, const unsigned short* __restrict__ Xl,
    const float* __restrict__ bias, const float* __restrict__ attn,
    unsigned short* __restrict__ Oh, unsigned short* __restrict__ Ol) {
  int t = threadIdx.x, wv = t >> 6, lane = t & 63;
  int col = lane & 15, g = lane >> 4;
  int ry = blockIdx.x;                 // 0..1023
  int b = ry >> 8, y = ry & 255;
  int x0 = wv * 64;
  f32x4 acc[6][4];
#pragma unroll
  for (int m = 0; m < 6; ++m)
#pragma unroll
    for (int n = 0; n < 4; ++n) acc[m][n] = (f32x4)0.f;

  unsigned gxo[4][3];
#pragma unroll
  for (int nf = 0; nf < 4; ++nf)
#pragma unroll
    for (int dx = 0; dx < 3; ++dx) {
      int xx = x0 + nf * 16 + col + dx - 1;
      xx = xx < 0 ? 1 : (xx > 255 ? 254 : xx);
      gxo[nf][dx] = (unsigned)xx * 192u + (unsigned)g * 16u;
    }
  size_t bbase = (size_t)b * kHW * 192;

#pragma unroll 1
  for (int dy = 0; dy < 3; ++dy) {
    int yy = y + dy - 1;
    yy = yy < 0 ? 1 : (yy > 255 ? 254 : yy);
    const char* bh = (const char*)Xh + bbase + (size_t)yy * 256 * 192;
    const char* bl = (const char*)Xl + bbase + (size_t)yy * 256 * 192;
#pragma unroll
    for (int dx = 0; dx < 3; ++dx) {
      const char* ah = (const char*)Wh + ((size_t)(dy * 3 + dx) * 9216 + col * 96 + g * 8) * 2;
      const char* al = (const char*)Wl + ((size_t)(dy * 3 + dx) * 9216 + col * 96 + g * 8) * 2;
#pragma unroll
      for (int ks = 0; ks < 3; ++ks) {
        short8 Ahf[6], Alf[6], Bhf[4], Blf[4];
#pragma unroll
        for (int mf = 0; mf < 6; ++mf) {
          Ahf[mf] = *(const short8*)(ah + (size_t)(mf * 16 * 96 + ks * 32) * 2);
          Alf[mf] = *(const short8*)(al + (size_t)(mf * 16 * 96 + ks * 32) * 2);
        }
#pragma unroll
        for (int nf = 0; nf < 4; ++nf) {
          Bhf[nf] = *(const short8*)(bh + gxo[nf][dx] + ks * 64);
          Blf[nf] = *(const short8*)(bl + gxo[nf][dx] + ks * 64);
        }
#pragma unroll
        for (int mf = 0; mf < 6; ++mf)
#pragma unroll
          for (int nf = 0; nf < 4; ++nf) {
            acc[mf][nf] = __builtin_amdgcn_mfma_f32_16x16x32_bf16(Ahf[mf], Bhf[nf], acc[mf][nf], 0, 0, 0);
            acc[mf][nf] = __builtin_amdgcn_mfma_f32_16x16x32_bf16(Ahf[mf], Blf[nf], acc[mf][nf], 0, 0, 0);
            acc[mf][nf] = __builtin_amdgcn_mfma_f32_16x16x32_bf16(Alf[mf], Bhf[nf], acc[mf][nf], 0, 0, 0);
          }
      }
    }
  }

  size_t prow = (size_t)b * kHW + (size_t)y * 256;
#pragma unroll
  for (int mf = 0; mf < 6; ++mf) {
    int oc0 = mf * 16 + g * 4;
    f32x4 bv;
#pragma unroll
    for (int r = 0; r < 4; ++r) bv[r] = bias[oc0 + r];
#pragma unroll
    for (int nf = 0; nf < 4; ++nf) {
      size_t p = prow + x0 + nf * 16 + col;
      size_t off = p * 96 + oc0;
      f32x4 v = acc[mf][nf] + bv;
      if (MODE == 0) {
#pragma unroll
        for (int r = 0; r < 4; ++r) v[r] = fmaxf(v[r], 0.f);
      } else {
        float4 a = *(const float4*)(attn + off);
        v[0] += a.x; v[1] += a.y; v[2] += a.z; v[3] += a.w;
      }
      us4 oh, ol;
#pragma unroll
      for (int r = 0; r < 4; ++r) { unsigned short hh, ll; split2(v[r], hh, ll); oh[r] = hh; ol[r] = ll; }
      *(us4*)(Oh + off) = oh;
      *(us4*)(Ol + off) = ol;
    }
  }
}

// ---------------- final projection -> d_out NCHW fp32 ------------------------
__global__ __launch_bounds__(256, 2) void proj_gemm(
    const unsigned short* __restrict__ Wph, const unsigned short* __restrict__ Wpl,
    const unsigned short* __restrict__ Sh, const unsigned short* __restrict__ Sl,
    const float* __restrict__ bias, float* __restrict__ out) {
  int t = threadIdx.x, wv = t >> 6, lane = t & 63;
  size_t px0 = (size_t)blockIdx.x * 256 + wv * 64;
  f32x4 acc[6][4];
#pragma unroll
  for (int m = 0; m < 6; ++m)
#pragma unroll
    for (int n = 0; n < 4; ++n) acc[m][n] = (f32x4)0.f;
  gemm_core(Wph, Wpl, Sh, Sl, px0, lane, acc);
  int col = lane & 15, g = lane >> 4;
#pragma unroll
  for (int mf = 0; mf < 6; ++mf) {
    int oc0 = mf * 16 + g * 4;
#pragma unroll
    for (int nf = 0; nf < 4; ++nf) {
      size_t p = px0 + nf * 16 + col;
      size_t bb = p >> 16, pix = p & 65535;
      f32x4 v = acc[mf][nf];
#pragma unroll
      for (int r = 0; r < 4; ++r)
        out[(bb * 96 + oc0 + r) * (size_t)kHW + pix] = v[r] + bias[oc0 + r];
    }
  }
}

extern "C" void kernel_launch(void* const* d_in, const int* in_sizes, int n_in,
                              void* d_out, int out_size, void* d_ws, size_t ws_size,
                              hipStream_t stream) {
  const float* X       = (const float*)d_in[0];
  const float* V_w     = (const float*)d_in[1];
  const float* V_b     = (const float*)d_in[2];
  const float* QK_w    = (const float*)d_in[3];
  const float* QK_b    = (const float*)d_in[4];
  const float* meta_w1 = (const float*)d_in[5];
  const float* meta_b1 = (const float*)d_in[6];
  const float* meta_w2 = (const float*)d_in[7];
  const float* meta_b2 = (const float*)d_in[8];
  const float* conv1_w = (const float*)d_in[9];
  const float* conv1_b = (const float*)d_in[10];
  const float* conv2_w = (const float*)d_in[11];
  const float* conv2_b = (const float*)d_in[12];
  const float* proj_w  = (const float*)d_in[13];
  const float* proj_b  = (const float*)d_in[14];
  float* out = (float*)d_out;

  char* w = (char*)d_ws;
  const size_t PLANE = (size_t)kP * 96 * 2;      // 50,331,648 B
  unsigned short* Xh = (unsigned short*)(w + 0 * PLANE);
  unsigned short* Xl = (unsigned short*)(w + 1 * PLANE);
  unsigned short* Qb = (unsigned short*)(w + 2 * PLANE);
  unsigned short* Kb = (unsigned short*)(w + 3 * PLANE);
  unsigned short* Vh = (unsigned short*)(w + 4 * PLANE);
  unsigned short* Vl = (unsigned short*)(w + 5 * PLANE);
  float* bias_tab    = (float*)(w + 6 * PLANE);
  unsigned short* Wqh = (unsigned short*)(w + 6 * PLANE + 98304);
  unsigned short* Wql = Wqh + 27648;
  unsigned short* W1h = Wql + 27648;
  unsigned short* W1l = W1h + 82944;
  unsigned short* W2h = W1l + 82944;
  unsigned short* W2l = W2h + 82944;
  unsigned short* Wph = W2l + 82944;
  unsigned short* Wpl = Wph + 9216;
  // aliases (stream-ordered reuse)
  unsigned short* T1h = Xh;  unsigned short* T1l = Xl;   // X dead after qkv
  unsigned short* S2h = Qb;  unsigned short* S2l = Kb;   // Q/K dead after attn
  float* attnNHWC = out;                                  // d_out as scratch; proj overwrites

  bias_kernel<<<dim3(64), dim3(64), 0, stream>>>(meta_w1, meta_b1, meta_w2, meta_b2, bias_tab);
  prep_weights<<<dim3(324), dim3(256), 0, stream>>>(QK_w, V_w, conv1_w, conv2_w, proj_w,
                                                    Wqh, Wql, W1h, W1l, W2h, W2l, Wph, Wpl);
  split_x<<<dim3(4096), dim3(256), 0, stream>>>(X, Xh, Xl);
  qkv_gemm<<<dim3(1024, 3), dim3(256), 0, stream>>>(Wqh, Wql, Xh, Xl, QK_b, V_b, Qb, Kb, Vh, Vl);
  attn_kernel<<<dim3(1024, 6), dim3(256), 0, stream>>>(Qb, Kb, Vh, Vl, bias_tab, attnNHWC);
  conv_gemm<0><<<dim3(1024), dim3(256), 0, stream>>>(W1h, W1l, Vh, Vl, conv1_b, nullptr, T1h, T1l);
  conv_gemm<1><<<dim3(1024), dim3(256), 0, stream>>>(W2h, W2l, T1h, T1l, conv2_b, attnNHWC, S2h, S2l);
  proj_gemm<<<dim3(1024), dim3(256), 0, stream>>>(Wph, Wpl, S2h, S2l, proj_b, out);
}

// Round 3
// 932.202 us; speedup vs baseline: 3.3688x; 1.4984x over previous
//
#include <hip/hip_runtime.h>
#include <cmath>

typedef short  short8 __attribute__((ext_vector_type(8)));
typedef float  f32x4  __attribute__((ext_vector_type(4)));
typedef unsigned short us8 __attribute__((ext_vector_type(8)));
typedef unsigned short us4 __attribute__((ext_vector_type(4)));

constexpr int kHW = 65536;           // 256*256
constexpr int kP  = 262144;          // 4 * kHW total pixels

__device__ __forceinline__ unsigned short f2bf(float x) {
  unsigned u = __builtin_bit_cast(unsigned, x);
  u += 0x7fffu + ((u >> 16) & 1u);
  return (unsigned short)(u >> 16);
}
__device__ __forceinline__ float bf2f(unsigned short h) {
  unsigned u = ((unsigned)h) << 16;
  return __builtin_bit_cast(float, u);
}
__device__ __forceinline__ void split2(float v, unsigned short& h, unsigned short& l) {
  unsigned short hh = f2bf(v);
  h = hh;
  l = f2bf(v - bf2f(hh));
}

// ---------------- bias table: bias_tab[h][i][j], h<6, i,j<64 ----------------
__global__ void bias_kernel(const float* __restrict__ w1, const float* __restrict__ b1,
                            const float* __restrict__ w2, const float* __restrict__ b2,
                            float* __restrict__ bias_tab) {
  int i = blockIdx.x;
  int j = threadIdx.x;
  float dy = (float)((i >> 3) - (j >> 3));
  float dx = (float)((i & 7) - (j & 7));
  float r0 = copysignf(log1pf(fabsf(dy)), dy);
  float r1 = copysignf(log1pf(fabsf(dx)), dx);
  float acc[6];
#pragma unroll
  for (int h = 0; h < 6; ++h) acc[h] = b2[h];
  for (int t = 0; t < 256; ++t) {
    float hv = fmaf(r0, w1[t], fmaf(r1, w1[256 + t], b1[t]));
    hv = fmaxf(hv, 0.f);
#pragma unroll
    for (int h = 0; h < 6; ++h) acc[h] = fmaf(hv, w2[t * 6 + h], acc[h]);
  }
#pragma unroll
  for (int h = 0; h < 6; ++h) bias_tab[h * 4096 + i * 64 + j] = acc[h];
}

// ---------------- weight prep: fp32 -> bf16 hi/lo planes ---------------------
__global__ void prep_weights(const float* __restrict__ qk_w, const float* __restrict__ v_w,
                             const float* __restrict__ c1w, const float* __restrict__ c2w,
                             const float* __restrict__ pjw,
                             unsigned short* __restrict__ Wqh, unsigned short* __restrict__ Wql,
                             unsigned short* __restrict__ W1h, unsigned short* __restrict__ W1l,
                             unsigned short* __restrict__ W2h, unsigned short* __restrict__ W2l,
                             unsigned short* __restrict__ Wph, unsigned short* __restrict__ Wpl) {
  int i = blockIdx.x * 256 + threadIdx.x;
  if (i < 27648) {
    float v = (i < 18432) ? qk_w[i] : v_w[i - 18432];
    split2(v, Wqh[i], Wql[i]);
  }
  if (i < 82944) {
    int dlt = i / 9216;
    int oc  = (i / 96) % 96;
    int ic  = i % 96;
    int src = (oc * 96 + ic) * 9 + dlt;
    split2(c1w[src], W1h[i], W1l[i]);
    split2(c2w[src], W2h[i], W2l[i]);
  }
  if (i < 9216) split2(pjw[i], Wph[i], Wpl[i]);
}

// ---------------- X: NCHW fp32 -> NHWC bf16 hi/lo ---------------------------
__global__ __launch_bounds__(256) void split_x(const float* __restrict__ X,
                                               unsigned short* __restrict__ Xh,
                                               unsigned short* __restrict__ Xl) {
  __shared__ float tile[96][65];
  int t = threadIdx.x;
  size_t p0 = (size_t)blockIdx.x * 64;
  int b = (int)(p0 >> 16), pix = (int)(p0 & 65535);
  const float* xb = X + (size_t)b * 96 * kHW + pix;
#pragma unroll
  for (int i = 0; i < 24; ++i) {
    int ic = (t >> 6) + i * 4;
    tile[ic][t & 63] = xb[(size_t)ic * kHW + (t & 63)];
  }
  __syncthreads();
  int px = t >> 2;
  size_t outbase = (p0 + px) * 96;
#pragma unroll
  for (int cc = 0; cc < 3; ++cc) {
    int c = (t & 3) + cc * 4;
    us8 h8, l8;
#pragma unroll
    for (int j = 0; j < 8; ++j) {
      unsigned short hh, ll;
      split2(tile[c * 8 + j][px], hh, ll);
      h8[j] = hh; l8[j] = ll;
    }
    *(us8*)(Xh + outbase + c * 8) = h8;
    *(us8*)(Xl + outbase + c * 8) = l8;
  }
}

// ---------------- shared MFMA core: D[96 oc][64 px] ------------------------
// A: W[oc][96] hi/lo (rows k-fastest). B: act [p][96] (cols k-fastest).
// BLO=true: 3-term hh+hl+lh.  BLO=false: 2-term (Wh+Wl)*Bh.
template <bool BLO>
__device__ __forceinline__ void gemm_core(
    const unsigned short* __restrict__ Wh, const unsigned short* __restrict__ Wl,
    const unsigned short* __restrict__ Xh, const unsigned short* __restrict__ Xl,
    size_t px0, int lane, f32x4 (&acc)[6][4]) {
  int col = lane & 15, g = lane >> 4;
  const char* aH = (const char*)Wh + (size_t)(col * 96 + g * 8) * 2;
  const char* aL = (const char*)Wl + (size_t)(col * 96 + g * 8) * 2;
  const char* bH = (const char*)Xh + ((px0 + col) * 96 + g * 8) * 2;
  const char* bL = (const char*)Xl + ((px0 + col) * 96 + g * 8) * 2;
#pragma unroll
  for (int ks = 0; ks < 3; ++ks) {
    short8 Ahf[6], Alf[6], Bhf[4], Blf[4];
#pragma unroll
    for (int mf = 0; mf < 6; ++mf) {
      Ahf[mf] = *(const short8*)(aH + (size_t)(mf * 16 * 96 + ks * 32) * 2);
      Alf[mf] = *(const short8*)(aL + (size_t)(mf * 16 * 96 + ks * 32) * 2);
    }
#pragma unroll
    for (int nf = 0; nf < 4; ++nf) {
      Bhf[nf] = *(const short8*)(bH + (size_t)(nf * 16 * 96 + ks * 32) * 2);
      if (BLO) Blf[nf] = *(const short8*)(bL + (size_t)(nf * 16 * 96 + ks * 32) * 2);
    }
#pragma unroll
    for (int mf = 0; mf < 6; ++mf)
#pragma unroll
      for (int nf = 0; nf < 4; ++nf) {
        acc[mf][nf] = __builtin_amdgcn_mfma_f32_16x16x32_bf16(Ahf[mf], Bhf[nf], acc[mf][nf], 0, 0, 0);
        if (BLO)
          acc[mf][nf] = __builtin_amdgcn_mfma_f32_16x16x32_bf16(Ahf[mf], Blf[nf], acc[mf][nf], 0, 0, 0);
        acc[mf][nf] = __builtin_amdgcn_mfma_f32_16x16x32_bf16(Alf[mf], Bhf[nf], acc[mf][nf], 0, 0, 0);
      }
  }
}

// ---------------- QKV GEMM: z=0 Q*0.25, z=1 K, z=2 V ------------------------
// Q,K,V written head-planar [h][p][16] bf16; V additionally row [p][96] bf16.
__global__ __launch_bounds__(256, 2) void qkv_gemm(
    const unsigned short* __restrict__ Wqh, const unsigned short* __restrict__ Wql,
    const unsigned short* __restrict__ Xh, const unsigned short* __restrict__ Xl,
    const float* __restrict__ qk_b, const float* __restrict__ v_b,
    unsigned short* __restrict__ Qp, unsigned short* __restrict__ Kp,
    unsigned short* __restrict__ Vp, unsigned short* __restrict__ Vr) {
  int t = threadIdx.x, wv = t >> 6, lane = t & 63;
  int z = blockIdx.y;
  size_t px0 = (size_t)blockIdx.x * 256 + wv * 64;
  f32x4 acc[6][4];
#pragma unroll
  for (int m = 0; m < 6; ++m)
#pragma unroll
    for (int n = 0; n < 4; ++n) acc[m][n] = (f32x4)0.f;
  gemm_core<true>(Wqh + z * 9216, Wql + z * 9216, Xh, Xl, px0, lane, acc);
  int col = lane & 15, g = lane >> 4;
  const float* bias = (z == 0) ? qk_b : (z == 1 ? qk_b + 96 : v_b);
  float scale = (z == 0) ? 0.25f : 1.f;
#pragma unroll
  for (int mf = 0; mf < 6; ++mf) {
    int oc0 = mf * 16 + g * 4;
    f32x4 bv;
#pragma unroll
    for (int r = 0; r < 4; ++r) bv[r] = bias[oc0 + r];
#pragma unroll
    for (int nf = 0; nf < 4; ++nf) {
      size_t p = px0 + nf * 16 + col;
      f32x4 v = (acc[mf][nf] + bv) * scale;
      us4 o;
#pragma unroll
      for (int r = 0; r < 4; ++r) o[r] = f2bf(v[r]);
      size_t hoff = ((size_t)mf * kP + p) * 16 + g * 4;   // head = mf
      if (z == 0)      *(us4*)(Qp + hoff) = o;
      else if (z == 1) *(us4*)(Kp + hoff) = o;
      else {
        *(us4*)(Vp + hoff) = o;
        *(us4*)(Vr + p * 96 + oc0) = o;
      }
    }
  }
}

// ---------------- attention: head-planar bf16 in, head-planar f32 out -------
__global__ __launch_bounds__(256) void attn_kernel(
    const unsigned short* __restrict__ Qp, const unsigned short* __restrict__ Kp,
    const unsigned short* __restrict__ Vp, const float* __restrict__ bias_tab,
    float* __restrict__ out) {
  __shared__ float bs[64 * 65];
  __shared__ float ks_[4][64 * 16];
  __shared__ float vs_[4][64 * 16];
  int t = threadIdx.x;
  int wv = t >> 6, lane = t & 63;
  int h = blockIdx.y;
  int wid = blockIdx.x * 4 + wv;
  int b = wid >> 10, wy = (wid >> 5) & 31, wx = wid & 31;
  size_t p = ((size_t)b << 16) + (size_t)(wy * 8 + (lane >> 3)) * 256 + wx * 8 + (lane & 7);
  size_t base = ((size_t)h * kP + p) * 16;
  us8 q0 = *(const us8*)(Qp + base), q1 = *(const us8*)(Qp + base + 8);
  us8 k0 = *(const us8*)(Kp + base), k1 = *(const us8*)(Kp + base + 8);
  us8 v0 = *(const us8*)(Vp + base), v1 = *(const us8*)(Vp + base + 8);
  float q[16];
#pragma unroll
  for (int d = 0; d < 8; ++d) {
    q[d]     = bf2f(q0[d]);          // already scaled by 0.25 in qkv
    q[8 + d] = bf2f(q1[d]);
  }
  float4* kr4 = (float4*)&ks_[wv][lane * 16];
  float4* vr4 = (float4*)&vs_[wv][lane * 16];
#pragma unroll
  for (int d4 = 0; d4 < 2; ++d4) {
    kr4[d4]     = make_float4(bf2f(k0[d4*4]), bf2f(k0[d4*4+1]), bf2f(k0[d4*4+2]), bf2f(k0[d4*4+3]));
    kr4[2 + d4] = make_float4(bf2f(k1[d4*4]), bf2f(k1[d4*4+1]), bf2f(k1[d4*4+2]), bf2f(k1[d4*4+3]));
    vr4[d4]     = make_float4(bf2f(v0[d4*4]), bf2f(v0[d4*4+1]), bf2f(v0[d4*4+2]), bf2f(v0[d4*4+3]));
    vr4[2 + d4] = make_float4(bf2f(v1[d4*4]), bf2f(v1[d4*4+1]), bf2f(v1[d4*4+2]), bf2f(v1[d4*4+3]));
  }
  {
    const float* bp = bias_tab + h * 4096;
#pragma unroll
    for (int r0 = 0; r0 < 16; ++r0) {
      int r = wv * 16 + r0;
      bs[r * 65 + lane] = bp[r * 64 + lane];
    }
  }
  __syncthreads();

  const float* krow = ks_[wv];
  const float* vrow = vs_[wv];
  float s[64];
#pragma unroll 8
  for (int j = 0; j < 64; ++j) {
    float dot = bs[lane * 65 + j];
#pragma unroll
    for (int d = 0; d < 16; ++d) dot = fmaf(q[d], krow[j * 16 + d], dot);
    s[j] = dot;
  }
  float m = s[0];
#pragma unroll
  for (int j = 1; j < 64; ++j) m = fmaxf(m, s[j]);
  float sum = 0.f;
#pragma unroll
  for (int j = 0; j < 64; ++j) { s[j] = expf(s[j] - m); sum += s[j]; }
  float r = 1.f / sum;
  float o[16];
#pragma unroll
  for (int d = 0; d < 16; ++d) o[d] = 0.f;
#pragma unroll 8
  for (int j = 0; j < 64; ++j) {
    float pj = s[j];
#pragma unroll
    for (int d = 0; d < 16; ++d) o[d] = fmaf(pj, vrow[j * 16 + d], o[d]);
  }
  float* op = out + base;
#pragma unroll
  for (int d = 0; d < 16; ++d) op[d] = o[d] * r;
}

// ---------------- 3x3 reflect conv as 9 shifted 2-term MFMA GEMMs -----------
// MODE 0: +bias, relu -> bf16 row out.  MODE 1: +bias +attn(f32 head-planar) -> bf16 row out.
template <int MODE>
__global__ __launch_bounds__(256, 2) void conv_gemm(
    const unsigned short* __restrict__ Wh, const unsigned short* __restrict__ Wl,
    const unsigned short* __restrict__ B_, const float* __restrict__ bias,
    const float* __restrict__ attn, unsigned short* __restrict__ O_) {
  int t = threadIdx.x, wv = t >> 6, lane = t & 63;
  int col = lane & 15, g = lane >> 4;
  int ry = blockIdx.x;                 // 0..1023
  int b = ry >> 8, y = ry & 255;
  int x0 = wv * 64;
  f32x4 acc[6][4];
#pragma unroll
  for (int m = 0; m < 6; ++m)
#pragma unroll
    for (int n = 0; n < 4; ++n) acc[m][n] = (f32x4)0.f;

  unsigned gxo[4][3];
#pragma unroll
  for (int nf = 0; nf < 4; ++nf)
#pragma unroll
    for (int dx = 0; dx < 3; ++dx) {
      int xx = x0 + nf * 16 + col + dx - 1;
      xx = xx < 0 ? 1 : (xx > 255 ? 254 : xx);
      gxo[nf][dx] = (unsigned)xx * 192u + (unsigned)g * 16u;
    }
  size_t bbase = (size_t)b * kHW * 192;

#pragma unroll 1
  for (int dy = 0; dy < 3; ++dy) {
    int yy = y + dy - 1;
    yy = yy < 0 ? 1 : (yy > 255 ? 254 : yy);
    const char* bh = (const char*)B_ + bbase + (size_t)yy * 256 * 192;
#pragma unroll
    for (int dx = 0; dx < 3; ++dx) {
      const char* ah = (const char*)Wh + ((size_t)(dy * 3 + dx) * 9216 + col * 96 + g * 8) * 2;
      const char* al = (const char*)Wl + ((size_t)(dy * 3 + dx) * 9216 + col * 96 + g * 8) * 2;
#pragma unroll
      for (int ks = 0; ks < 3; ++ks) {
        short8 Ahf[6], Alf[6], Bhf[4];
#pragma unroll
        for (int mf = 0; mf < 6; ++mf) {
          Ahf[mf] = *(const short8*)(ah + (size_t)(mf * 16 * 96 + ks * 32) * 2);
          Alf[mf] = *(const short8*)(al + (size_t)(mf * 16 * 96 + ks * 32) * 2);
        }
#pragma unroll
        for (int nf = 0; nf < 4; ++nf)
          Bhf[nf] = *(const short8*)(bh + gxo[nf][dx] + ks * 64);
#pragma unroll
        for (int mf = 0; mf < 6; ++mf)
#pragma unroll
          for (int nf = 0; nf < 4; ++nf) {
            acc[mf][nf] = __builtin_amdgcn_mfma_f32_16x16x32_bf16(Ahf[mf], Bhf[nf], acc[mf][nf], 0, 0, 0);
            acc[mf][nf] = __builtin_amdgcn_mfma_f32_16x16x32_bf16(Alf[mf], Bhf[nf], acc[mf][nf], 0, 0, 0);
          }
      }
    }
  }

  size_t prow = (size_t)b * kHW + (size_t)y * 256;
#pragma unroll
  for (int mf = 0; mf < 6; ++mf) {
    int oc0 = mf * 16 + g * 4;
    f32x4 bv;
#pragma unroll
    for (int r = 0; r < 4; ++r) bv[r] = bias[oc0 + r];
#pragma unroll
    for (int nf = 0; nf < 4; ++nf) {
      size_t p = prow + x0 + nf * 16 + col;
      f32x4 v = acc[mf][nf] + bv;
      if (MODE == 0) {
#pragma unroll
        for (int r = 0; r < 4; ++r) v[r] = fmaxf(v[r], 0.f);
      } else {
        float4 a = *(const float4*)(attn + ((size_t)mf * kP + p) * 16 + g * 4);
        v[0] += a.x; v[1] += a.y; v[2] += a.z; v[3] += a.w;
      }
      us4 o;
#pragma unroll
      for (int r = 0; r < 4; ++r) o[r] = f2bf(v[r]);
      *(us4*)(O_ + p * 96 + oc0) = o;
    }
  }
}

// ---------------- final projection -> d_out NCHW fp32 ------------------------
__global__ __launch_bounds__(256, 2) void proj_gemm(
    const unsigned short* __restrict__ Wph, const unsigned short* __restrict__ Wpl,
    const unsigned short* __restrict__ S_, const float* __restrict__ bias,
    float* __restrict__ out) {
  int t = threadIdx.x, wv = t >> 6, lane = t & 63;
  size_t px0 = (size_t)blockIdx.x * 256 + wv * 64;
  f32x4 acc[6][4];
#pragma unroll
  for (int m = 0; m < 6; ++m)
#pragma unroll
    for (int n = 0; n < 4; ++n) acc[m][n] = (f32x4)0.f;
  gemm_core<false>(Wph, Wpl, S_, S_, px0, lane, acc);
  int col = lane & 15, g = lane >> 4;
#pragma unroll
  for (int mf = 0; mf < 6; ++mf) {
    int oc0 = mf * 16 + g * 4;
#pragma unroll
    for (int nf = 0; nf < 4; ++nf) {
      size_t p = px0 + nf * 16 + col;
      size_t bb = p >> 16, pix = p & 65535;
      f32x4 v = acc[mf][nf];
#pragma unroll
      for (int r = 0; r < 4; ++r)
        out[(bb * 96 + oc0 + r) * (size_t)kHW + pix] = v[r] + bias[oc0 + r];
    }
  }
}

extern "C" void kernel_launch(void* const* d_in, const int* in_sizes, int n_in,
                              void* d_out, int out_size, void* d_ws, size_t ws_size,
                              hipStream_t stream) {
  const float* X       = (const float*)d_in[0];
  const float* V_w     = (const float*)d_in[1];
  const float* V_b     = (const float*)d_in[2];
  const float* QK_w    = (const float*)d_in[3];
  const float* QK_b    = (const float*)d_in[4];
  const float* meta_w1 = (const float*)d_in[5];
  const float* meta_b1 = (const float*)d_in[6];
  const float* meta_w2 = (const float*)d_in[7];
  const float* meta_b2 = (const float*)d_in[8];
  const float* conv1_w = (const float*)d_in[9];
  const float* conv1_b = (const float*)d_in[10];
  const float* conv2_w = (const float*)d_in[11];
  const float* conv2_b = (const float*)d_in[12];
  const float* proj_w  = (const float*)d_in[13];
  const float* proj_b  = (const float*)d_in[14];
  float* out = (float*)d_out;

  char* w = (char*)d_ws;
  const size_t PLANE = (size_t)kP * 96 * 2;      // 50,331,648 B
  unsigned short* Xh = (unsigned short*)(w + 0 * PLANE);
  unsigned short* Xl = (unsigned short*)(w + 1 * PLANE);
  unsigned short* Qp = (unsigned short*)(w + 2 * PLANE);
  unsigned short* Kp = (unsigned short*)(w + 3 * PLANE);
  unsigned short* Vp = (unsigned short*)(w + 4 * PLANE);
  unsigned short* Vr = (unsigned short*)(w + 5 * PLANE);
  float* bias_tab    = (float*)(w + 6 * PLANE);
  unsigned short* Wqh = (unsigned short*)(w + 6 * PLANE + 98304);
  unsigned short* Wql = Wqh + 27648;
  unsigned short* W1h = Wql + 27648;
  unsigned short* W1l = W1h + 82944;
  unsigned short* W2h = W1l + 82944;
  unsigned short* W2l = W2h + 82944;
  unsigned short* Wph = W2l + 82944;
  unsigned short* Wpl = Wph + 9216;
  // stream-ordered aliases
  unsigned short* T1r = Xh;            // X dead after qkv_gemm
  unsigned short* S2r = Qp;            // Q dead after attn
  float* attnF = out;                  // d_out as head-planar f32 scratch; proj overwrites

  bias_kernel<<<dim3(64), dim3(64), 0, stream>>>(meta_w1, meta_b1, meta_w2, meta_b2, bias_tab);
  prep_weights<<<dim3(324), dim3(256), 0, stream>>>(QK_w, V_w, conv1_w, conv2_w, proj_w,
                                                    Wqh, Wql, W1h, W1l, W2h, W2l, Wph, Wpl);
  split_x<<<dim3(4096), dim3(256), 0, stream>>>(X, Xh, Xl);
  qkv_gemm<<<dim3(1024, 3), dim3(256), 0, stream>>>(Wqh, Wql, Xh, Xl, QK_b, V_b, Qp, Kp, Vp, Vr);
  attn_kernel<<<dim3(1024, 6), dim3(256), 0, stream>>>(Qp, Kp, Vp, bias_tab, attnF);
  conv_gemm<0><<<dim3(1024), dim3(256), 0, stream>>>(W1h, W1l, Vr, conv1_b, nullptr, T1r);
  conv_gemm<1><<<dim3(1024), dim3(256), 0, stream>>>(W2h, W2l, T1r, conv2_b, attnF, S2r);
  proj_gemm<<<dim3(1024), dim3(256), 0, stream>>>(Wph, Wpl, S2r, proj_b, out);
}

// Round 4
// 694.814 us; speedup vs baseline: 4.5197x; 1.3417x over previous
//
#include <hip/hip_runtime.h>
#include <cmath>

typedef short  short8 __attribute__((ext_vector_type(8)));
typedef float  f32x4  __attribute__((ext_vector_type(4)));
typedef unsigned short us8 __attribute__((ext_vector_type(8)));
typedef unsigned short us4 __attribute__((ext_vector_type(4)));

constexpr int kHW = 65536;           // 256*256
constexpr int kP  = 262144;          // 4 * kHW total pixels

__device__ __forceinline__ unsigned short f2bf(float x) {
  unsigned u = __builtin_bit_cast(unsigned, x);
  u += 0x7fffu + ((u >> 16) & 1u);
  return (unsigned short)(u >> 16);
}
__device__ __forceinline__ float bf2f(unsigned short h) {
  unsigned u = ((unsigned)h) << 16;
  return __builtin_bit_cast(float, u);
}
__device__ __forceinline__ void split2(float v, unsigned short& h, unsigned short& l) {
  unsigned short hh = f2bf(v);
  h = hh;
  l = f2bf(v - bf2f(hh));
}

// ---------------- bias table: bias_tab[h][i][j], h<6, i,j<64 ----------------
__global__ void bias_kernel(const float* __restrict__ w1, const float* __restrict__ b1,
                            const float* __restrict__ w2, const float* __restrict__ b2,
                            float* __restrict__ bias_tab) {
  int i = blockIdx.x;
  int j = threadIdx.x;
  float dy = (float)((i >> 3) - (j >> 3));
  float dx = (float)((i & 7) - (j & 7));
  float r0 = copysignf(log1pf(fabsf(dy)), dy);
  float r1 = copysignf(log1pf(fabsf(dx)), dx);
  float acc[6];
#pragma unroll
  for (int h = 0; h < 6; ++h) acc[h] = b2[h];
  for (int t = 0; t < 256; ++t) {
    float hv = fmaf(r0, w1[t], fmaf(r1, w1[256 + t], b1[t]));
    hv = fmaxf(hv, 0.f);
#pragma unroll
    for (int h = 0; h < 6; ++h) acc[h] = fmaf(hv, w2[t * 6 + h], acc[h]);
  }
#pragma unroll
  for (int h = 0; h < 6; ++h) bias_tab[h * 4096 + i * 64 + j] = acc[h];
}

// ---------------- weight prep: fp32 -> bf16 hi/lo planes ---------------------
__global__ void prep_weights(const float* __restrict__ qk_w, const float* __restrict__ v_w,
                             const float* __restrict__ c1w, const float* __restrict__ c2w,
                             const float* __restrict__ pjw,
                             unsigned short* __restrict__ Wqh, unsigned short* __restrict__ Wql,
                             unsigned short* __restrict__ W1h, unsigned short* __restrict__ W1l,
                             unsigned short* __restrict__ W2h, unsigned short* __restrict__ W2l,
                             unsigned short* __restrict__ Wph, unsigned short* __restrict__ Wpl) {
  int i = blockIdx.x * 256 + threadIdx.x;
  if (i < 27648) {
    float v = (i < 18432) ? qk_w[i] : v_w[i - 18432];
    split2(v, Wqh[i], Wql[i]);
  }
  if (i < 82944) {
    int dlt = i / 9216;
    int oc  = (i / 96) % 96;
    int ic  = i % 96;
    int src = (oc * 96 + ic) * 9 + dlt;
    split2(c1w[src], W1h[i], W1l[i]);
    split2(c2w[src], W2h[i], W2l[i]);
  }
  if (i < 9216) split2(pjw[i], Wph[i], Wpl[i]);
}

// ---------------- X: NCHW fp32 -> NHWC bf16 hi/lo ---------------------------
__global__ __launch_bounds__(256) void split_x(const float* __restrict__ X,
                                               unsigned short* __restrict__ Xh,
                                               unsigned short* __restrict__ Xl) {
  __shared__ float tile[96][65];
  int t = threadIdx.x;
  size_t p0 = (size_t)blockIdx.x * 64;
  int b = (int)(p0 >> 16), pix = (int)(p0 & 65535);
  const float* xb = X + (size_t)b * 96 * kHW + pix;
#pragma unroll
  for (int i = 0; i < 24; ++i) {
    int ic = (t >> 6) + i * 4;
    tile[ic][t & 63] = xb[(size_t)ic * kHW + (t & 63)];
  }
  __syncthreads();
  int px = t >> 2;
  size_t outbase = (p0 + px) * 96;
#pragma unroll
  for (int cc = 0; cc < 3; ++cc) {
    int c = (t & 3) + cc * 4;
    us8 h8, l8;
#pragma unroll
    for (int j = 0; j < 8; ++j) {
      unsigned short hh, ll;
      split2(tile[c * 8 + j][px], hh, ll);
      h8[j] = hh; l8[j] = ll;
    }
    *(us8*)(Xh + outbase + c * 8) = h8;
    *(us8*)(Xl + outbase + c * 8) = l8;
  }
}

// ---------------- shared MFMA core: D[96 oc][64 px] ------------------------
template <bool BLO>
__device__ __forceinline__ void gemm_core(
    const unsigned short* __restrict__ Wh, const unsigned short* __restrict__ Wl,
    const unsigned short* __restrict__ Xh, const unsigned short* __restrict__ Xl,
    size_t px0, int lane, f32x4 (&acc)[6][4]) {
  int col = lane & 15, g = lane >> 4;
  const char* aH = (const char*)Wh + (size_t)(col * 96 + g * 8) * 2;
  const char* aL = (const char*)Wl + (size_t)(col * 96 + g * 8) * 2;
  const char* bH = (const char*)Xh + ((px0 + col) * 96 + g * 8) * 2;
  const char* bL = (const char*)Xl + ((px0 + col) * 96 + g * 8) * 2;
#pragma unroll
  for (int ks = 0; ks < 3; ++ks) {
    short8 Ahf[6], Alf[6], Bhf[4], Blf[4];
#pragma unroll
    for (int mf = 0; mf < 6; ++mf) {
      Ahf[mf] = *(const short8*)(aH + (size_t)(mf * 16 * 96 + ks * 32) * 2);
      Alf[mf] = *(const short8*)(aL + (size_t)(mf * 16 * 96 + ks * 32) * 2);
    }
#pragma unroll
    for (int nf = 0; nf < 4; ++nf) {
      Bhf[nf] = *(const short8*)(bH + (size_t)(nf * 16 * 96 + ks * 32) * 2);
      if (BLO) Blf[nf] = *(const short8*)(bL + (size_t)(nf * 16 * 96 + ks * 32) * 2);
    }
#pragma unroll
    for (int mf = 0; mf < 6; ++mf)
#pragma unroll
      for (int nf = 0; nf < 4; ++nf) {
        acc[mf][nf] = __builtin_amdgcn_mfma_f32_16x16x32_bf16(Ahf[mf], Bhf[nf], acc[mf][nf], 0, 0, 0);
        if (BLO)
          acc[mf][nf] = __builtin_amdgcn_mfma_f32_16x16x32_bf16(Ahf[mf], Blf[nf], acc[mf][nf], 0, 0, 0);
        acc[mf][nf] = __builtin_amdgcn_mfma_f32_16x16x32_bf16(Alf[mf], Bhf[nf], acc[mf][nf], 0, 0, 0);
      }
  }
}

// ---------------- QKV GEMM: z=0 Q*0.25, z=1 K, z=2 V ------------------------
__global__ __launch_bounds__(256, 2) void qkv_gemm(
    const unsigned short* __restrict__ Wqh, const unsigned short* __restrict__ Wql,
    const unsigned short* __restrict__ Xh, const unsigned short* __restrict__ Xl,
    const float* __restrict__ qk_b, const float* __restrict__ v_b,
    unsigned short* __restrict__ Qp, unsigned short* __restrict__ Kp,
    unsigned short* __restrict__ Vp, unsigned short* __restrict__ Vr) {
  int t = threadIdx.x, wv = t >> 6, lane = t & 63;
  int z = blockIdx.y;
  size_t px0 = (size_t)blockIdx.x * 256 + wv * 64;
  f32x4 acc[6][4];
#pragma unroll
  for (int m = 0; m < 6; ++m)
#pragma unroll
    for (int n = 0; n < 4; ++n) acc[m][n] = (f32x4)0.f;
  gemm_core<true>(Wqh + z * 9216, Wql + z * 9216, Xh, Xl, px0, lane, acc);
  int col = lane & 15, g = lane >> 4;
  const float* bias = (z == 0) ? qk_b : (z == 1 ? qk_b + 96 : v_b);
  float scale = (z == 0) ? 0.25f : 1.f;
#pragma unroll
  for (int mf = 0; mf < 6; ++mf) {
    int oc0 = mf * 16 + g * 4;
    f32x4 bv;
#pragma unroll
    for (int r = 0; r < 4; ++r) bv[r] = bias[oc0 + r];
#pragma unroll
    for (int nf = 0; nf < 4; ++nf) {
      size_t p = px0 + nf * 16 + col;
      f32x4 v = (acc[mf][nf] + bv) * scale;
      us4 o;
#pragma unroll
      for (int r = 0; r < 4; ++r) o[r] = f2bf(v[r]);
      size_t hoff = ((size_t)mf * kP + p) * 16 + g * 4;   // head = mf
      if (z == 0)      *(us4*)(Qp + hoff) = o;
      else if (z == 1) *(us4*)(Kp + hoff) = o;
      else {
        *(us4*)(Vp + hoff) = o;
        *(us4*)(Vr + p * 96 + oc0) = o;
      }
    }
  }
}

// ---------------- attention: reg-resident scores, conflict-free LDS ---------
__global__ __launch_bounds__(256) void attn_kernel(
    const unsigned short* __restrict__ Qp, const unsigned short* __restrict__ Kp,
    const unsigned short* __restrict__ Vp, const float* __restrict__ bias_tab,
    float* __restrict__ out) {
  __shared__ float bs[64 * 65];
  __shared__ float4 kls[4][4][64];   // [wv][d4][j] - write lane-stride 16B, read broadcast
  __shared__ float4 vls[4][4][64];
  int t = threadIdx.x;
  int wv = t >> 6, lane = t & 63;
  int h = blockIdx.y;
  int wid = blockIdx.x * 4 + wv;
  int b = wid >> 10, wy = (wid >> 5) & 31, wx = wid & 31;
  size_t p = ((size_t)b << 16) + (size_t)(wy * 8 + (lane >> 3)) * 256 + wx * 8 + (lane & 7);
  size_t base = ((size_t)h * kP + p) * 16;
  us8 q0 = *(const us8*)(Qp + base), q1 = *(const us8*)(Qp + base + 8);
  us8 k0 = *(const us8*)(Kp + base), k1 = *(const us8*)(Kp + base + 8);
  us8 v0 = *(const us8*)(Vp + base), v1 = *(const us8*)(Vp + base + 8);
  float q[16];
#pragma unroll
  for (int d = 0; d < 8; ++d) {
    q[d]     = bf2f(q0[d]);          // already scaled by 0.25 in qkv
    q[8 + d] = bf2f(q1[d]);
  }
  kls[wv][0][lane] = make_float4(bf2f(k0[0]), bf2f(k0[1]), bf2f(k0[2]), bf2f(k0[3]));
  kls[wv][1][lane] = make_float4(bf2f(k0[4]), bf2f(k0[5]), bf2f(k0[6]), bf2f(k0[7]));
  kls[wv][2][lane] = make_float4(bf2f(k1[0]), bf2f(k1[1]), bf2f(k1[2]), bf2f(k1[3]));
  kls[wv][3][lane] = make_float4(bf2f(k1[4]), bf2f(k1[5]), bf2f(k1[6]), bf2f(k1[7]));
  vls[wv][0][lane] = make_float4(bf2f(v0[0]), bf2f(v0[1]), bf2f(v0[2]), bf2f(v0[3]));
  vls[wv][1][lane] = make_float4(bf2f(v0[4]), bf2f(v0[5]), bf2f(v0[6]), bf2f(v0[7]));
  vls[wv][2][lane] = make_float4(bf2f(v1[0]), bf2f(v1[1]), bf2f(v1[2]), bf2f(v1[3]));
  vls[wv][3][lane] = make_float4(bf2f(v1[4]), bf2f(v1[5]), bf2f(v1[6]), bf2f(v1[7]));
  {
    const float* bp = bias_tab + h * 4096;
#pragma unroll
    for (int r0 = 0; r0 < 16; ++r0) {
      int r = wv * 16 + r0;
      bs[r * 65 + lane] = bp[r * 64 + lane];
    }
  }
  __syncthreads();

  const float* brow = bs + lane * 65;
  float s[64];
#pragma unroll
  for (int j = 0; j < 64; ++j) {
    float kk[16];
    *(float4*)&kk[0]  = kls[wv][0][j];
    *(float4*)&kk[4]  = kls[wv][1][j];
    *(float4*)&kk[8]  = kls[wv][2][j];
    *(float4*)&kk[12] = kls[wv][3][j];
    float dot = brow[j];
#pragma unroll
    for (int d = 0; d < 16; ++d) dot = fmaf(q[d], kk[d], dot);
    s[j] = dot;
  }
  float m = s[0];
#pragma unroll
  for (int j = 1; j < 64; ++j) m = fmaxf(m, s[j]);
  float sum = 0.f;
#pragma unroll
  for (int j = 0; j < 64; ++j) { s[j] = __expf(s[j] - m); sum += s[j]; }
  float r = 1.f / sum;
  float o[16];
#pragma unroll
  for (int d = 0; d < 16; ++d) o[d] = 0.f;
#pragma unroll
  for (int j = 0; j < 64; ++j) {
    float vv[16];
    *(float4*)&vv[0]  = vls[wv][0][j];
    *(float4*)&vv[4]  = vls[wv][1][j];
    *(float4*)&vv[8]  = vls[wv][2][j];
    *(float4*)&vv[12] = vls[wv][3][j];
    float pj = s[j];
#pragma unroll
    for (int d = 0; d < 16; ++d) o[d] = fmaf(pj, vv[d], o[d]);
  }
#pragma unroll
  for (int d = 0; d < 16; ++d) o[d] *= r;
  float* op = out + base;
  *(float4*)(op)      = *(float4*)&o[0];
  *(float4*)(op + 4)  = *(float4*)&o[4];
  *(float4*)(op + 8)  = *(float4*)&o[8];
  *(float4*)(op + 12) = *(float4*)&o[12];
}

// ---------------- 3x3 reflect conv as 9 shifted 2-term MFMA GEMMs -----------
template <int MODE>
__global__ __launch_bounds__(256, 2) void conv_gemm(
    const unsigned short* __restrict__ Wh, const unsigned short* __restrict__ Wl,
    const unsigned short* __restrict__ B_, const float* __restrict__ bias,
    const float* __restrict__ attn, unsigned short* __restrict__ O_) {
  int t = threadIdx.x, wv = t >> 6, lane = t & 63;
  int col = lane & 15, g = lane >> 4;
  int bid = blockIdx.x;
  int ry = (bid & 7) * 128 + (bid >> 3);   // XCD-chunked: 128 consecutive rows per XCD
  int b = ry >> 8, y = ry & 255;
  int x0 = wv * 64;
  f32x4 acc[6][4];
#pragma unroll
  for (int m = 0; m < 6; ++m)
#pragma unroll
    for (int n = 0; n < 4; ++n) acc[m][n] = (f32x4)0.f;

  unsigned gxo[4][3];
#pragma unroll
  for (int nf = 0; nf < 4; ++nf)
#pragma unroll
    for (int dx = 0; dx < 3; ++dx) {
      int xx = x0 + nf * 16 + col + dx - 1;
      xx = xx < 0 ? 1 : (xx > 255 ? 254 : xx);
      gxo[nf][dx] = (unsigned)xx * 192u + (unsigned)g * 16u;
    }
  size_t bbase = (size_t)b * kHW * 192;

#pragma unroll 1
  for (int dy = 0; dy < 3; ++dy) {
    int yy = y + dy - 1;
    yy = yy < 0 ? 1 : (yy > 255 ? 254 : yy);
    const char* bh = (const char*)B_ + bbase + (size_t)yy * 256 * 192;
#pragma unroll
    for (int dx = 0; dx < 3; ++dx) {
      const char* ah = (const char*)Wh + ((size_t)(dy * 3 + dx) * 9216 + col * 96 + g * 8) * 2;
      const char* al = (const char*)Wl + ((size_t)(dy * 3 + dx) * 9216 + col * 96 + g * 8) * 2;
#pragma unroll
      for (int ks = 0; ks < 3; ++ks) {
        short8 Ahf[6], Alf[6], Bhf[4];
#pragma unroll
        for (int mf = 0; mf < 6; ++mf) {
          Ahf[mf] = *(const short8*)(ah + (size_t)(mf * 16 * 96 + ks * 32) * 2);
          Alf[mf] = *(const short8*)(al + (size_t)(mf * 16 * 96 + ks * 32) * 2);
        }
#pragma unroll
        for (int nf = 0; nf < 4; ++nf)
          Bhf[nf] = *(const short8*)(bh + gxo[nf][dx] + ks * 64);
#pragma unroll
        for (int mf = 0; mf < 6; ++mf)
#pragma unroll
          for (int nf = 0; nf < 4; ++nf) {
            acc[mf][nf] = __builtin_amdgcn_mfma_f32_16x16x32_bf16(Ahf[mf], Bhf[nf], acc[mf][nf], 0, 0, 0);
            acc[mf][nf] = __builtin_amdgcn_mfma_f32_16x16x32_bf16(Alf[mf], Bhf[nf], acc[mf][nf], 0, 0, 0);
          }
      }
    }
  }

  size_t prow = (size_t)b * kHW + (size_t)y * 256;
#pragma unroll
  for (int mf = 0; mf < 6; ++mf) {
    int oc0 = mf * 16 + g * 4;
    f32x4 bv;
#pragma unroll
    for (int r = 0; r < 4; ++r) bv[r] = bias[oc0 + r];
#pragma unroll
    for (int nf = 0; nf < 4; ++nf) {
      size_t p = prow + x0 + nf * 16 + col;
      f32x4 v = acc[mf][nf] + bv;
      if (MODE == 0) {
#pragma unroll
        for (int r = 0; r < 4; ++r) v[r] = fmaxf(v[r], 0.f);
      } else {
        float4 a = *(const float4*)(attn + ((size_t)mf * kP + p) * 16 + g * 4);
        v[0] += a.x; v[1] += a.y; v[2] += a.z; v[3] += a.w;
      }
      us4 o;
#pragma unroll
      for (int r = 0; r < 4; ++r) o[r] = f2bf(v[r]);
      *(us4*)(O_ + p * 96 + oc0) = o;
    }
  }
}

// ---------------- final projection -> d_out NCHW fp32 ------------------------
__global__ __launch_bounds__(256, 2) void proj_gemm(
    const unsigned short* __restrict__ Wph, const unsigned short* __restrict__ Wpl,
    const unsigned short* __restrict__ S_, const float* __restrict__ bias,
    float* __restrict__ out) {
  int t = threadIdx.x, wv = t >> 6, lane = t & 63;
  size_t px0 = (size_t)blockIdx.x * 256 + wv * 64;
  f32x4 acc[6][4];
#pragma unroll
  for (int m = 0; m < 6; ++m)
#pragma unroll
    for (int n = 0; n < 4; ++n) acc[m][n] = (f32x4)0.f;
  gemm_core<false>(Wph, Wpl, S_, S_, px0, lane, acc);
  int col = lane & 15, g = lane >> 4;
#pragma unroll
  for (int mf = 0; mf < 6; ++mf) {
    int oc0 = mf * 16 + g * 4;
#pragma unroll
    for (int nf = 0; nf < 4; ++nf) {
      size_t p = px0 + nf * 16 + col;
      size_t bb = p >> 16, pix = p & 65535;
      f32x4 v = acc[mf][nf];
#pragma unroll
      for (int r = 0; r < 4; ++r)
        out[(bb * 96 + oc0 + r) * (size_t)kHW + pix] = v[r] + bias[oc0 + r];
    }
  }
}

extern "C" void kernel_launch(void* const* d_in, const int* in_sizes, int n_in,
                              void* d_out, int out_size, void* d_ws, size_t ws_size,
                              hipStream_t stream) {
  const float* X       = (const float*)d_in[0];
  const float* V_w     = (const float*)d_in[1];
  const float* V_b     = (const float*)d_in[2];
  const float* QK_w    = (const float*)d_in[3];
  const float* QK_b    = (const float*)d_in[4];
  const float* meta_w1 = (const float*)d_in[5];
  const float* meta_b1 = (const float*)d_in[6];
  const float* meta_w2 = (const float*)d_in[7];
  const float* meta_b2 = (const float*)d_in[8];
  const float* conv1_w = (const float*)d_in[9];
  const float* conv1_b = (const float*)d_in[10];
  const float* conv2_w = (const float*)d_in[11];
  const float* conv2_b = (const float*)d_in[12];
  const float* proj_w  = (const float*)d_in[13];
  const float* proj_b  = (const float*)d_in[14];
  float* out = (float*)d_out;

  char* w = (char*)d_ws;
  const size_t PLANE = (size_t)kP * 96 * 2;      // 50,331,648 B
  unsigned short* Xh = (unsigned short*)(w + 0 * PLANE);
  unsigned short* Xl = (unsigned short*)(w + 1 * PLANE);
  unsigned short* Qp = (unsigned short*)(w + 2 * PLANE);
  unsigned short* Kp = (unsigned short*)(w + 3 * PLANE);
  unsigned short* Vp = (unsigned short*)(w + 4 * PLANE);
  unsigned short* Vr = (unsigned short*)(w + 5 * PLANE);
  float* bias_tab    = (float*)(w + 6 * PLANE);
  unsigned short* Wqh = (unsigned short*)(w + 6 * PLANE + 98304);
  unsigned short* Wql = Wqh + 27648;
  unsigned short* W1h = Wql + 27648;
  unsigned short* W1l = W1h + 82944;
  unsigned short* W2h = W1l + 82944;
  unsigned short* W2l = W2h + 82944;
  unsigned short* Wph = W2l + 82944;
  unsigned short* Wpl = Wph + 9216;
  // stream-ordered aliases
  unsigned short* T1r = Xh;            // X dead after qkv_gemm
  unsigned short* S2r = Qp;            // Q dead after attn
  float* attnF = out;                  // d_out as head-planar f32 scratch; proj overwrites

  bias_kernel<<<dim3(64), dim3(64), 0, stream>>>(meta_w1, meta_b1, meta_w2, meta_b2, bias_tab);
  prep_weights<<<dim3(324), dim3(256), 0, stream>>>(QK_w, V_w, conv1_w, conv2_w, proj_w,
                                                    Wqh, Wql, W1h, W1l, W2h, W2l, Wph, Wpl);
  split_x<<<dim3(4096), dim3(256), 0, stream>>>(X, Xh, Xl);
  qkv_gemm<<<dim3(1024, 3), dim3(256), 0, stream>>>(Wqh, Wql, Xh, Xl, QK_b, V_b, Qp, Kp, Vp, Vr);
  attn_kernel<<<dim3(1024, 6), dim3(256), 0, stream>>>(Qp, Kp, Vp, bias_tab, attnF);
  conv_gemm<0><<<dim3(1024), dim3(256), 0, stream>>>(W1h, W1l, Vr, conv1_b, nullptr, T1r);
  conv_gemm<1><<<dim3(1024), dim3(256), 0, stream>>>(W2h, W2l, T1r, conv2_b, attnF, S2r);
  proj_gemm<<<dim3(1024), dim3(256), 0, stream>>>(Wph, Wpl, S2r, proj_b, out);
}